// Round 10
// baseline (1674.676 us; speedup 1.0000x reference)
//
#include <hip/hip_runtime.h>
#include <math.h>

// LSTM autoencoder, MFMA fp16, R10: producer-consumer LAYER PIPELINING.
// 128 blocks x 1024 threads (16 waves, 4/SIMD), BT=16 rows/block.
// Encoder: waves0-7 z1(t)+cell1 || waves8-11 z2(t-1)+cell2 -- ONE barrier/step.
// Decoder: waves0-7 z4(tau-1)+cell4 || waves8-11 z3(tau)+cell3 || wave12
// dense(tau-2) -- one barrier/step. All tile sets gate-aligned -> every cell
// in-register (ZSC scratch eliminated). Partial AGPR pins within the 128-reg
// cap that 16-wave blocks force; remaining weight frags streamed from L2
// (R8 showed streaming is ~free when overlapped). fp16 numerics (R9, floor).

typedef _Float16 half8 __attribute__((ext_vector_type(8)));
typedef __attribute__((ext_vector_type(4))) float floatx4;

#define TT 128
#define NF 8
#define BT 16
#define NBLK 128
#define NTH 1024

// packed-fragment start indices (in 512-ushort frag units, single fp16 plane)
#define FS_Z1 0     // K'=160 (Wr1 128 | Wk1 8 | pad), N=512 : 32 tiles x 5 ks
#define FS_Z2 160   // K'=192 (Wk2 128 | Wr2 64),     N=256 : 16 x 6
#define FS_X3 256   // K =64  (Wk3),                  N=256 : 16 x 2
#define FS_Z3 288   // K =64  (Wr3),                  N=256 : 16 x 2
#define FS_Z4 320   // K'=192 (Wk4 64 | Wr4 128),     N=512 : 32 x 6
#define FS_DN 512   // K =128 (Wd), N=16 (cols 8-15 zero) : 1 x 4
#define N_FRAGS 516

#define MFMAH(a,b,c) __builtin_amdgcn_mfma_f32_16x16x32_f16((a),(b),(c),0,0,0)
#define PINA(v) asm volatile("" : "+a"(v))

__device__ __forceinline__ float sigmoid_(float x){ return 1.0f/(1.0f+__expf(-x)); }
__device__ __forceinline__ float selu_(float x){
    const float alpha = 1.6732632423543772f, scale = 1.0507009873554805f;
    return x > 0.0f ? scale*x : scale*alpha*(__expf(x)-1.0f);
}

// ---------------- pack kernel: RAW weights -> B-fragment order, fp16 --------
__global__ void pack_kernel(const float* __restrict__ Wk1, const float* __restrict__ Wr1,
                            const float* __restrict__ Wk2, const float* __restrict__ Wr2,
                            const float* __restrict__ Wk3, const float* __restrict__ Wr3,
                            const float* __restrict__ Wk4, const float* __restrict__ Wr4,
                            const float* __restrict__ Wd, unsigned short* __restrict__ ws)
{
    const int g = blockIdx.x;
    const int l = threadIdx.x;
    int blob, fs, KS;
    if      (g < FS_Z2){ blob = 0; fs = FS_Z1; KS = 5; }
    else if (g < FS_X3){ blob = 1; fs = FS_Z2; KS = 6; }
    else if (g < FS_Z3){ blob = 2; fs = FS_X3; KS = 2; }
    else if (g < FS_Z4){ blob = 3; fs = FS_Z3; KS = 2; }
    else if (g < FS_DN){ blob = 4; fs = FS_Z4; KS = 6; }
    else               { blob = 5; fs = FS_DN; KS = 4; }
    const int fl = g - fs;
    const int tile = fl / KS, kk = fl % KS;
    const int col = tile * 16 + (l & 15);
    const int k0  = kk * 32 + (l >> 4) * 8;

    half8 v8;
    #pragma unroll
    for (int j = 0; j < 8; ++j){
        const int k = k0 + j;
        float v = 0.0f;
        switch (blob){
            case 0: v = (k < 128) ? Wr1[k*512 + col] : (k < 136 ? Wk1[(k-128)*512 + col] : 0.0f); break;
            case 1: v = (k < 128) ? Wk2[k*256 + col] : Wr2[(k-128)*256 + col]; break;
            case 2: v = Wk3[k*256 + col]; break;
            case 3: v = Wr3[k*256 + col]; break;
            case 4: v = (k < 64) ? Wk4[k*512 + col] : Wr4[(k-64)*512 + col]; break;
            case 5: v = (col < 8) ? Wd[k*8 + col] : 0.0f; break;
        }
        v8[j] = (_Float16)v;    // RNE
    }
    *(half8*)(ws + (size_t)g*512 + l*8) = v8;
}

// ---------------- main kernel ------------------------------------------------
__global__ __launch_bounds__(NTH, 4) void lstm_ae_mfma(
    const float* __restrict__ x,
    const float* __restrict__ b1, const float* __restrict__ b2,
    const float* __restrict__ b3, const float* __restrict__ b4,
    const float* __restrict__ bd,
    const float* __restrict__ g1, const float* __restrict__ be1, const float* __restrict__ m1, const float* __restrict__ v1,
    const float* __restrict__ g2, const float* __restrict__ be2, const float* __restrict__ m2, const float* __restrict__ v2,
    const float* __restrict__ g3, const float* __restrict__ be3, const float* __restrict__ m3, const float* __restrict__ v3,
    const float* __restrict__ g4, const float* __restrict__ be4, const float* __restrict__ m4, const float* __restrict__ v4,
    const unsigned short* __restrict__ WS,
    float* __restrict__ out)
{
    // A-fragment planes, fp16: [ping][kk][lane*8 + j]
    __shared__ __align__(16) _Float16 AZ1[2][5][512];   // h1 (kk0-3) + x (kk4)
    __shared__ __align__(16) _Float16 AH1B[2][4][512];  // BN1(h1), ping-pong
    __shared__ __align__(16) _Float16 AH2[2][2][512];   // h2
    __shared__ __align__(16) _Float16 AH3[2][2][512];   // h3
    __shared__ __align__(16) _Float16 AH3B[2][2][512];  // BN3(h3); [1] holds encb pre-decoder
    __shared__ __align__(16) _Float16 AH4[2][4][512];   // h4
    __shared__ __align__(16) _Float16 AH4B[2][4][512];  // BN4(h4)

    const int tid = threadIdx.x;
    const int w = tid >> 6, l = tid & 63;
    const int l15 = l & 15, q = l >> 4;
    const int w2 = w & 3;
    const int b0 = blockIdx.x * BT;

    // ---- zero all state planes ----
    for (int i = tid; i < 2560; i += NTH) ((int*)AZ1)[i] = 0;
    for (int i = tid; i < 2048; i += NTH){ ((int*)AH1B)[i] = 0; ((int*)AH4)[i] = 0; ((int*)AH4B)[i] = 0; }
    for (int i = tid; i < 1024; i += NTH){ ((int*)AH2)[i] = 0; ((int*)AH3)[i] = 0; ((int*)AH3B)[i] = 0; }
    __syncthreads();
    if (tid < 128){
        int row = tid >> 3, j = tid & 7;
        AZ1[0][4][row*8+j] = (_Float16)x[(size_t)(b0+row)*(TT*NF) + j];
    }

    // ---- role constants ----
    int u1 = 0, kk1 = 0, sb1 = 0;
    float s1v=0,t1v=0,s4v=0,t4v=0;
    float z1b[4]={0,0,0,0}, z4b[4]={0,0,0,0};
    int kk2 = 0, sb2 = 0;
    float s2v=0,t2v=0,s3v=0,t3v=0;
    float z2b[4]={0,0,0,0}, b3v[4]={0,0,0,0};
    float bdv = 0.0f;

    half8 wz1p[4][3];               // encoder pins: z1 kk0-2 (48 AGPR)
    if (w < 8){
        u1 = 16*w + l15; kk1 = u1 >> 5; sb1 = ((u1>>3)&3)*128 + (u1&7);
        s1v = g1[u1]*rsqrtf(v1[u1]+1e-3f); t1v = be1[u1]-m1[u1]*s1v;
        s4v = g4[u1]*rsqrtf(v4[u1]+1e-3f); t4v = be4[u1]-m4[u1]*s4v;
        #pragma unroll
        for (int i = 0; i < 4; ++i){ z1b[i] = b1[(w+8*i)*16 + l15]; z4b[i] = b4[(w+8*i)*16 + l15]; }
        #pragma unroll
        for (int i = 0; i < 4; ++i)
            #pragma unroll
            for (int kk = 0; kk < 3; ++kk){
                wz1p[i][kk] = *(const half8*)(WS + (size_t)(FS_Z1 + (w+8*i)*5 + kk)*512 + l*8);
                PINA(wz1p[i][kk]);
            }
    } else if (w < 12){
        const int u2 = 16*w2 + l15;
        kk2 = u2 >> 5; sb2 = ((u2>>3)&3)*128 + (u2&7);
        s2v = g2[u2]*rsqrtf(v2[u2]+1e-3f); t2v = be2[u2]-m2[u2]*s2v;
        s3v = g3[u2]*rsqrtf(v3[u2]+1e-3f); t3v = be3[u2]-m3[u2]*s3v;
        #pragma unroll
        for (int i = 0; i < 4; ++i){ z2b[i] = b2[(w2+4*i)*16 + l15]; b3v[i] = b3[(w2+4*i)*16 + l15]; }
    } else if (w == 12){
        bdv = (l15 < 8) ? bd[l15] : 0.0f;
    }

    float c1r[4]={0,0,0,0}, c2r[4]={0,0,0,0}, c3r[4]={0,0,0,0}, c4r[4]={0,0,0,0};
    __syncthreads();

    // ============ encoder: TT+1 pipelined iterations, 1 barrier each ========
    int p = 0;
    for (int t = 0; t <= TT; ++t){
        if (w < 8){
            if (t < TT){
                float xnext = 0.0f;
                if (tid < 128 && t+1 < TT)
                    xnext = x[(size_t)(b0+(tid>>3))*(TT*NF) + (size_t)(t+1)*NF + (tid&7)];
                floatx4 acc[4];
                #pragma unroll
                for (int i = 0; i < 4; ++i) acc[i] = (floatx4){z1b[i],z1b[i],z1b[i],z1b[i]};
                #pragma unroll
                for (int kk = 0; kk < 3; ++kk){
                    half8 a = *(const half8*)&AZ1[p][kk][l*8];
                    #pragma unroll
                    for (int i = 0; i < 4; ++i) acc[i] = MFMAH(a, wz1p[i][kk], acc[i]);
                }
                #pragma unroll
                for (int kk = 3; kk < 5; ++kk){      // streamed kks
                    half8 a = *(const half8*)&AZ1[p][kk][l*8];
                    #pragma unroll
                    for (int i = 0; i < 4; ++i){
                        half8 b = *(const half8*)(WS + (size_t)(FS_Z1 + (w+8*i)*5 + kk)*512 + l*8);
                        acc[i] = MFMAH(a, b, acc[i]);
                    }
                }
                #pragma unroll
                for (int r = 0; r < 4; ++r){
                    float ig = sigmoid_(acc[0][r]);
                    float fg = sigmoid_(acc[1][r]);
                    float gg = selu_(acc[2][r]);
                    float og = sigmoid_(acc[3][r]);
                    float c = fg*c1r[r] + ig*gg; c1r[r] = c;
                    float h = og*selu_(c);
                    const int s = sb1 + (q*4+r)*8;
                    AZ1[p^1][kk1][s]  = (_Float16)h;
                    AH1B[p^1][kk1][s] = (_Float16)(h*s1v + t1v);
                }
                if (tid < 128 && t+1 < TT)
                    AZ1[p^1][4][(tid>>3)*8 + (tid&7)] = (_Float16)xnext;
            }
        } else if (w < 12){
            if (t >= 1){                              // z2(t-1) + cell2
                floatx4 a2[4];
                #pragma unroll
                for (int i = 0; i < 4; ++i) a2[i] = (floatx4){z2b[i],z2b[i],z2b[i],z2b[i]};
                #pragma unroll
                for (int kk = 0; kk < 6; ++kk){
                    half8 a = (kk < 4) ? *(const half8*)&AH1B[p][kk][l*8]
                                       : *(const half8*)&AH2[p][kk-4][l*8];
                    #pragma unroll
                    for (int i = 0; i < 4; ++i){
                        half8 b = *(const half8*)(WS + (size_t)(FS_Z2 + (w2+4*i)*6 + kk)*512 + l*8);
                        a2[i] = MFMAH(a, b, a2[i]);
                    }
                }
                #pragma unroll
                for (int r = 0; r < 4; ++r){
                    float ig = sigmoid_(a2[0][r]);
                    float fg = sigmoid_(a2[1][r]);
                    float gg = selu_(a2[2][r]);
                    float og = sigmoid_(a2[3][r]);
                    float c = fg*c2r[r] + ig*gg; c2r[r] = c;
                    float h = og*selu_(c);
                    const int s = sb2 + (q*4+r)*8;
                    AH2[p^1][kk2][s] = (_Float16)h;
                    if (t == TT) AH3B[1][kk2][s] = (_Float16)(h*s2v + t2v);   // encb
                }
            }
        }
        __syncthreads();
        p ^= 1;
    }

    // ============ bottleneck: xz3 (waves 8-11) + decoder pins ===============
    floatx4 xz3r[4];
    half8 wz3p[4][2], wdnp[4], wz4p[4][3];
    if (w < 8){
        #pragma unroll
        for (int i = 0; i < 4; ++i)
            #pragma unroll
            for (int kk = 0; kk < 3; ++kk){          // z4 pins kk0-2 (48 AGPR)
                wz4p[i][kk] = *(const half8*)(WS + (size_t)(FS_Z4 + (w+8*i)*6 + kk)*512 + l*8);
                PINA(wz4p[i][kk]);
            }
    } else if (w < 12){
        #pragma unroll
        for (int i = 0; i < 4; ++i) xz3r[i] = (floatx4){b3v[i],b3v[i],b3v[i],b3v[i]};
        #pragma unroll
        for (int kk = 0; kk < 2; ++kk){
            half8 a = *(const half8*)&AH3B[1][kk][l*8];
            #pragma unroll
            for (int i = 0; i < 4; ++i){
                half8 b = *(const half8*)(WS + (size_t)(FS_X3 + (w2+4*i)*2 + kk)*512 + l*8);
                xz3r[i] = MFMAH(a, b, xz3r[i]);
            }
        }
        #pragma unroll
        for (int i = 0; i < 4; ++i)
            #pragma unroll
            for (int kk = 0; kk < 2; ++kk){
                wz3p[i][kk] = *(const half8*)(WS + (size_t)(FS_Z3 + (w2+4*i)*2 + kk)*512 + l*8);
                PINA(wz3p[i][kk]);
            }
    } else if (w == 12){
        #pragma unroll
        for (int kk = 0; kk < 4; ++kk){
            wdnp[kk] = *(const half8*)(WS + (size_t)(FS_DN + kk)*512 + l*8);
            PINA(wdnp[kk]);
        }
    }
    __syncthreads();   // xz3 reads of AH3B[1] complete before decoder overwrites

    // ============ decoder: TT+2 pipelined iterations, 1 barrier each ========
    p = 0;
    for (int tau = 0; tau <= TT+1; ++tau){
        if (w < 8){
            if (tau >= 1 && tau <= TT){               // z4(tau-1) + cell4
                floatx4 a4[4];
                #pragma unroll
                for (int i = 0; i < 4; ++i) a4[i] = (floatx4){z4b[i],z4b[i],z4b[i],z4b[i]};
                #pragma unroll
                for (int kk = 0; kk < 3; ++kk){       // pinned kks
                    half8 a = (kk < 2) ? *(const half8*)&AH3B[p][kk][l*8]
                                       : *(const half8*)&AH4[p][kk-2][l*8];
                    #pragma unroll
                    for (int i = 0; i < 4; ++i) a4[i] = MFMAH(a, wz4p[i][kk], a4[i]);
                }
                #pragma unroll
                for (int kk = 3; kk < 6; ++kk){       // streamed kks
                    half8 a = *(const half8*)&AH4[p][kk-2][l*8];
                    #pragma unroll
                    for (int i = 0; i < 4; ++i){
                        half8 b = *(const half8*)(WS + (size_t)(FS_Z4 + (w+8*i)*6 + kk)*512 + l*8);
                        a4[i] = MFMAH(a, b, a4[i]);
                    }
                }
                #pragma unroll
                for (int r = 0; r < 4; ++r){
                    float ig = sigmoid_(a4[0][r]);
                    float fg = sigmoid_(a4[1][r]);
                    float gg = selu_(a4[2][r]);
                    float og = sigmoid_(a4[3][r]);
                    float c = fg*c4r[r] + ig*gg; c4r[r] = c;
                    float h = og*selu_(c);
                    const int s = sb1 + (q*4+r)*8;
                    AH4[p^1][kk1][s]  = (_Float16)h;
                    AH4B[p^1][kk1][s] = (_Float16)(h*s4v + t4v);
                }
            }
        } else if (w < 12){
            if (tau < TT){                            // z3(tau) + cell3
                floatx4 a3[4];
                #pragma unroll
                for (int i = 0; i < 4; ++i) a3[i] = xz3r[i];
                #pragma unroll
                for (int kk = 0; kk < 2; ++kk){
                    half8 a = *(const half8*)&AH3[p][kk][l*8];
                    #pragma unroll
                    for (int i = 0; i < 4; ++i) a3[i] = MFMAH(a, wz3p[i][kk], a3[i]);
                }
                #pragma unroll
                for (int r = 0; r < 4; ++r){
                    float ig = sigmoid_(a3[0][r]);
                    float fg = sigmoid_(a3[1][r]);
                    float gg = selu_(a3[2][r]);
                    float og = sigmoid_(a3[3][r]);
                    float c = fg*c3r[r] + ig*gg; c3r[r] = c;
                    float h = og*selu_(c);
                    const int s = sb2 + (q*4+r)*8;
                    AH3[p^1][kk2][s]  = (_Float16)h;
                    AH3B[p^1][kk2][s] = (_Float16)(h*s3v + t3v);
                }
            }
        } else if (w == 12){
            if (tau >= 2){                            // dense(tau-2)
                floatx4 ad = (floatx4){bdv,bdv,bdv,bdv};
                #pragma unroll
                for (int kk = 0; kk < 4; ++kk){
                    half8 a = *(const half8*)&AH4B[p][kk][l*8];
                    ad = MFMAH(a, wdnp[kk], ad);
                }
                if (l15 < 8){
                    #pragma unroll
                    for (int r = 0; r < 4; ++r)
                        out[(size_t)(b0 + q*4 + r)*(TT*NF) + (size_t)(tau-2)*NF + l15] = ad[r];
                }
            }
        }
        __syncthreads();
        p ^= 1;
    }
}

extern "C" void kernel_launch(void* const* d_in, const int* in_sizes, int n_in,
                              void* d_out, int out_size, void* d_ws, size_t ws_size,
                              hipStream_t stream) {
    const float* x   = (const float*)d_in[0];
    const float* Wk1 = (const float*)d_in[1];  const float* Wr1 = (const float*)d_in[2];
    const float* b1  = (const float*)d_in[3];
    const float* g1  = (const float*)d_in[4];  const float* be1 = (const float*)d_in[5];
    const float* m1  = (const float*)d_in[6];  const float* v1  = (const float*)d_in[7];
    const float* Wk2 = (const float*)d_in[8];  const float* Wr2 = (const float*)d_in[9];
    const float* b2  = (const float*)d_in[10];
    const float* g2  = (const float*)d_in[11]; const float* be2 = (const float*)d_in[12];
    const float* m2  = (const float*)d_in[13]; const float* v2  = (const float*)d_in[14];
    const float* Wk3 = (const float*)d_in[15]; const float* Wr3 = (const float*)d_in[16];
    const float* b3  = (const float*)d_in[17];
    const float* g3  = (const float*)d_in[18]; const float* be3 = (const float*)d_in[19];
    const float* m3  = (const float*)d_in[20]; const float* v3  = (const float*)d_in[21];
    const float* Wk4 = (const float*)d_in[22]; const float* Wr4 = (const float*)d_in[23];
    const float* b4  = (const float*)d_in[24];
    const float* g4  = (const float*)d_in[25]; const float* be4 = (const float*)d_in[26];
    const float* m4  = (const float*)d_in[27]; const float* v4  = (const float*)d_in[28];
    const float* Wd  = (const float*)d_in[29]; const float* bd  = (const float*)d_in[30];

    unsigned short* ws = (unsigned short*)d_ws;

    pack_kernel<<<dim3(N_FRAGS), dim3(64), 0, stream>>>(Wk1, Wr1, Wk2, Wr2, Wk3, Wr3,
                                                        Wk4, Wr4, Wd, ws);
    lstm_ae_mfma<<<dim3(NBLK), dim3(NTH), 0, stream>>>(
        x, b1, b2, b3, b4, bd,
        g1, be1, m1, v1, g2, be2, m2, v2,
        g3, be3, m3, v3, g4, be4, m4, v4,
        (const unsigned short*)ws, (float*)d_out);
}

// Round 11
// 829.748 us; speedup vs baseline: 2.0183x; 2.0183x over previous
//
#include <hip/hip_runtime.h>
#include <math.h>

// LSTM autoencoder, MFMA fp16, R11:
//  - ONE barrier per step in both phases (hazard-graph verified): encoder
//    waves4-7 flow z1(t)->z1(t+1) while waves0-3 run z2(t)+cell2 (gate-
//    aligned, in-register, ZSC deleted). Decoder: {z3+cell3 w4-7 | bar |
//    dense(tau-1) w0 + z4+cell4 all}.
//  - inverse-BN fold: store ONLY hb=BN(h); recurrent weights row-scaled by
//    1/s at pack time, biases adjusted exactly in f32. Halves state writes,
//    deletes AH1B/AH3B/AH4B planes, removes one quantization of h.
//  - initial state planes hold t (hb(0)=BN(0)=t), not 0.
//  - pins: z1(80) z4(96) z3(32,w4-7) dense(16,w0); z2 streamed w/ anti-hoist.
// 128 blocks x 512 threads (8 waves), BT=16 rows/block. fp16 numerics (R9).

typedef _Float16 half8 __attribute__((ext_vector_type(8)));
typedef __attribute__((ext_vector_type(4))) float floatx4;

#define TT 128
#define NF 8
#define BT 16
#define NBLK 128
#define NTH 512

// packed-fragment start indices (in 512-ushort frag units)
#define FS_Z1 0     // K'=160 (Wr1/s1 128 | Wk1 8 | 0), N=512 : 32 tiles x 5 ks
#define FS_Z2 160   // K'=192 (Wk2 128 | Wr2 64),      N=256 : 16 x 6
#define FS_X3 256   // K =64  (Wk3),                   N=256 : 16 x 2
#define FS_Z3 288   // K =64  (Wr3/s3),                N=256 : 16 x 2
#define FS_Z4 320   // K'=192 (Wk4 64 | Wr4/s4 128),   N=512 : 32 x 6
#define FS_DN 512   // K =128 (Wd), N=16 (cols 8-15 zero) : 1 x 4
#define N_FRAGS 516
// float bias area at ushort offset N_FRAGS*512:
//   [0,512) b1' | [512,768) b3' | [768,1280) b4'

#define MFMAH(a,b,c) __builtin_amdgcn_mfma_f32_16x16x32_f16((a),(b),(c),0,0,0)
#define PINA(v) asm volatile("" : "+a"(v))

__device__ __forceinline__ float sigmoid_(float x){ return 1.0f/(1.0f+__expf(-x)); }
__device__ __forceinline__ float selu_(float x){
    const float alpha = 1.6732632423543772f, scale = 1.0507009873554805f;
    return x > 0.0f ? scale*x : scale*alpha*(__expf(x)-1.0f);
}

// ---------------- pack kernel -----------------------------------------------
__global__ void pack_kernel(const float* __restrict__ Wk1, const float* __restrict__ Wr1,
                            const float* __restrict__ Wk2, const float* __restrict__ Wr2,
                            const float* __restrict__ Wk3, const float* __restrict__ Wr3,
                            const float* __restrict__ Wk4, const float* __restrict__ Wr4,
                            const float* __restrict__ Wd,
                            const float* __restrict__ g1, const float* __restrict__ be1, const float* __restrict__ m1, const float* __restrict__ v1,
                            const float* __restrict__ g3, const float* __restrict__ be3, const float* __restrict__ m3, const float* __restrict__ v3,
                            const float* __restrict__ g4, const float* __restrict__ be4, const float* __restrict__ m4, const float* __restrict__ v4,
                            const float* __restrict__ b1, const float* __restrict__ b3,
                            const float* __restrict__ b4,
                            unsigned short* __restrict__ ws)
{
    const int g = blockIdx.x;
    const int l = threadIdx.x;

    if (g >= N_FRAGS){              // folded biases: b' = b - (t/s)@Wr (exact f32)
        const int bb = g - N_FRAGS;
        float* fb = (float*)(ws + (size_t)N_FRAGS*512);
        if (bb == 0){
            for (int c = l; c < 512; c += 64){
                float acc = b1[c];
                for (int k = 0; k < 128; ++k){
                    float s = g1[k]*rsqrtf(v1[k]+1e-3f);
                    float t = be1[k]-m1[k]*s;
                    acc -= (t/s) * Wr1[k*512 + c];
                }
                fb[c] = acc;
            }
        } else if (bb == 1){
            for (int c = l; c < 256; c += 64){
                float acc = b3[c];
                for (int k = 0; k < 64; ++k){
                    float s = g3[k]*rsqrtf(v3[k]+1e-3f);
                    float t = be3[k]-m3[k]*s;
                    acc -= (t/s) * Wr3[k*256 + c];
                }
                fb[512 + c] = acc;
            }
        } else {
            for (int c = l; c < 512; c += 64){
                float acc = b4[c];
                for (int k = 0; k < 128; ++k){
                    float s = g4[k]*rsqrtf(v4[k]+1e-3f);
                    float t = be4[k]-m4[k]*s;
                    acc -= (t/s) * Wr4[k*512 + c];
                }
                fb[768 + c] = acc;
            }
        }
        return;
    }

    int blob, fs, KS;
    if      (g < FS_Z2){ blob = 0; fs = FS_Z1; KS = 5; }
    else if (g < FS_X3){ blob = 1; fs = FS_Z2; KS = 6; }
    else if (g < FS_Z3){ blob = 2; fs = FS_X3; KS = 2; }
    else if (g < FS_Z4){ blob = 3; fs = FS_Z3; KS = 2; }
    else if (g < FS_DN){ blob = 4; fs = FS_Z4; KS = 6; }
    else               { blob = 5; fs = FS_DN; KS = 4; }
    const int fl = g - fs;
    const int tile = fl / KS, kk = fl % KS;
    const int col = tile * 16 + (l & 15);
    const int k0  = kk * 32 + (l >> 4) * 8;

    half8 v8;
    #pragma unroll
    for (int j = 0; j < 8; ++j){
        const int k = k0 + j;
        float v = 0.0f;
        switch (blob){
            case 0:
                if (k < 128)      v = Wr1[k*512 + col] / (g1[k]*rsqrtf(v1[k]+1e-3f));
                else if (k < 136) v = Wk1[(k-128)*512 + col];
                break;
            case 1: v = (k < 128) ? Wk2[k*256 + col] : Wr2[(k-128)*256 + col]; break;
            case 2: v = Wk3[k*256 + col]; break;
            case 3: v = Wr3[k*256 + col] / (g3[k]*rsqrtf(v3[k]+1e-3f)); break;
            case 4:
                if (k < 64) v = Wk4[k*512 + col];
                else        v = Wr4[(k-64)*512 + col] / (g4[k-64]*rsqrtf(v4[k-64]+1e-3f));
                break;
            case 5: v = (col < 8) ? Wd[k*8 + col] : 0.0f; break;
        }
        v8[j] = (_Float16)v;
    }
    *(half8*)(ws + (size_t)g*512 + l*8) = v8;
}

// ---------------- main kernel ------------------------------------------------
__global__ __launch_bounds__(NTH, 2) void lstm_ae_mfma(
    const float* __restrict__ x,
    const float* __restrict__ b2, const float* __restrict__ bd,
    const float* __restrict__ g1, const float* __restrict__ be1, const float* __restrict__ m1, const float* __restrict__ v1,
    const float* __restrict__ g2, const float* __restrict__ be2, const float* __restrict__ m2, const float* __restrict__ v2,
    const float* __restrict__ g3, const float* __restrict__ be3, const float* __restrict__ m3, const float* __restrict__ v3,
    const float* __restrict__ g4, const float* __restrict__ be4, const float* __restrict__ m4, const float* __restrict__ v4,
    const unsigned short* __restrict__ WS,
    float* __restrict__ out)
{
    // state planes (fp16, A-fragment layout): hb only (inverse-BN folded)
    __shared__ __align__(16) _Float16 AZ1[2][5][512];   // hb1 (kk0-3) + x (kk4)
    __shared__ __align__(16) _Float16 AH2[2][2][512];   // h2 raw
    __shared__ __align__(16) _Float16 AH3[2][2][512];   // hb3
    __shared__ __align__(16) _Float16 AH4[2][4][512];   // hb4
    __shared__ __align__(16) _Float16 ENCB[2][512];     // BN2(h2 final)

    const int tid = threadIdx.x;
    const int w = tid >> 6, l = tid & 63;
    const int l15 = l & 15, q = l >> 4;
    const int b0 = blockIdx.x * BT;
    const float* FB = (const float*)(WS + (size_t)N_FRAGS*512);

    // ---- role constants ----
    const int u1 = 16*w + l15;                 // z1/z4 cell column 0..127
    const int kk1 = u1 >> 5;
    const int sb1 = ((u1>>3)&3)*128 + (u1&7);
    const float s1v = g1[u1]*rsqrtf(v1[u1]+1e-3f), t1v = be1[u1]-m1[u1]*s1v;
    const float s4v = g4[u1]*rsqrtf(v4[u1]+1e-3f), t4v = be4[u1]-m4[u1]*s4v;

    float z1b[4], z4b[4];
    #pragma unroll
    for (int i = 0; i < 4; ++i){
        z1b[i] = FB[(w + 8*i)*16 + l15];
        z4b[i] = FB[768 + (w + 8*i)*16 + l15];
    }

    // waves 0-3: z2/cell2/encb
    int kk2 = 0, sb2 = 0;
    float s2v = 0, t2v = 0, z2b[4] = {0,0,0,0};
    if (w < 4){
        const int u2 = 16*w + l15;             // 0..63
        kk2 = u2 >> 5; sb2 = ((u2>>3)&3)*128 + (u2&7);
        s2v = g2[u2]*rsqrtf(v2[u2]+1e-3f); t2v = be2[u2]-m2[u2]*s2v;
        #pragma unroll
        for (int i = 0; i < 4; ++i) z2b[i] = b2[(4*i + w)*16 + l15];
    }
    // waves 4-7: z3/cell3
    const int w3 = w - 4;
    int kk3 = 0, sb3 = 0;
    float s3v = 0, t3v = 0, b3v[4] = {0,0,0,0};
    if (w >= 4){
        const int u3 = 16*w3 + l15;            // 0..63
        kk3 = u3 >> 5; sb3 = ((u3>>3)&3)*128 + (u3&7);
        s3v = g3[u3]*rsqrtf(v3[u3]+1e-3f); t3v = be3[u3]-m3[u3]*s3v;
        #pragma unroll
        for (int i = 0; i < 4; ++i) b3v[i] = FB[512 + (4*i + w3)*16 + l15];
    }
    const float bdv = (w == 0 && l15 < 8) ? bd[l15] : 0.0f;

    // ---- encoder pins: z1 (20 frags = 80 regs, all waves) ----
    half8 wz1p[4][5];
    #pragma unroll
    for (int i = 0; i < 4; ++i)
        #pragma unroll
        for (int kk = 0; kk < 5; ++kk){
            wz1p[i][kk] = *(const half8*)(WS + (size_t)(FS_Z1 + (w+8*i)*5 + kk)*512 + l*8);
            PINA(wz1p[i][kk]);
        }

    // ---- prologue: zero AZ1/AH2, t-init state planes, stage x(0) ----
    for (int i = tid; i < 2560; i += NTH) ((int*)AZ1)[i] = 0;
    for (int i = tid; i < 1024; i += NTH) ((int*)AH2)[i] = 0;
    __syncthreads();
    #pragma unroll
    for (int r = 0; r < 4; ++r){
        AZ1[0][kk1][sb1 + (q*4+r)*8] = (_Float16)t1v;   // hb1(-1) = t1
        AH4[0][kk1][sb1 + (q*4+r)*8] = (_Float16)t4v;   // hb4(-1) = t4
    }
    if (w >= 4){
        #pragma unroll
        for (int r = 0; r < 4; ++r)
            AH3[0][kk3][sb3 + (q*4+r)*8] = (_Float16)t3v;  // hb3(-1) = t3
    }
    if (tid < 128){
        int row = tid >> 3, j = tid & 7;
        AZ1[0][4][row*8+j] = (_Float16)x[(size_t)(b0+row)*(TT*NF) + j];
    }
    float c1r[4] = {0,0,0,0}, c2r[4] = {0,0,0,0};
    float c3r[4] = {0,0,0,0}, c4r[4] = {0,0,0,0};
    __syncthreads();

    // ============ encoder: ONE barrier/step ============
    int p = 0;
    for (int t = 0; t < TT; ++t){
        // --- A: z1(t) + cell1 (all waves) ---
        float xnext = 0.0f;
        if (tid < 128 && t+1 < TT)
            xnext = x[(size_t)(b0+(tid>>3))*(TT*NF) + (size_t)(t+1)*NF + (tid&7)];
        floatx4 acc[4];
        #pragma unroll
        for (int i = 0; i < 4; ++i) acc[i] = (floatx4){z1b[i],z1b[i],z1b[i],z1b[i]};
        #pragma unroll
        for (int kk = 0; kk < 5; ++kk){
            half8 a = *(const half8*)&AZ1[p][kk][l*8];
            #pragma unroll
            for (int i = 0; i < 4; ++i) acc[i] = MFMAH(a, wz1p[i][kk], acc[i]);
        }
        #pragma unroll
        for (int r = 0; r < 4; ++r){
            float ig = sigmoid_(acc[0][r]);
            float fg = sigmoid_(acc[1][r]);
            float gg = selu_(acc[2][r]);
            float og = sigmoid_(acc[3][r]);
            float c = fg*c1r[r] + ig*gg; c1r[r] = c;
            float h = og*selu_(c);
            AZ1[p^1][kk1][sb1 + (q*4+r)*8] = (_Float16)(h*s1v + t1v);  // hb1 only
        }
        if (tid < 128 && t+1 < TT)
            AZ1[p^1][4][(tid>>3)*8 + (tid&7)] = (_Float16)xnext;
        __syncthreads();

        // --- B: z2(t) + cell2 (waves 0-3; waves 4-7 proceed to z1(t+1)) ---
        if (w < 4){
            const unsigned short* wsz2 = WS;
            asm volatile("" : "+r"(wsz2));          // defeat loop-invariant hoist
            floatx4 a2[4];
            #pragma unroll
            for (int i = 0; i < 4; ++i) a2[i] = (floatx4){z2b[i],z2b[i],z2b[i],z2b[i]};
            #pragma unroll
            for (int kk = 0; kk < 6; ++kk){
                half8 a = (kk < 4) ? *(const half8*)&AZ1[p^1][kk][l*8]
                                   : *(const half8*)&AH2[p][kk-4][l*8];
                #pragma unroll
                for (int i = 0; i < 4; ++i){
                    half8 b = *(const half8*)(wsz2 + (size_t)(FS_Z2 + (4*i+w)*6 + kk)*512 + l*8);
                    a2[i] = MFMAH(a, b, a2[i]);
                }
            }
            #pragma unroll
            for (int r = 0; r < 4; ++r){
                float ig = sigmoid_(a2[0][r]);
                float fg = sigmoid_(a2[1][r]);
                float gg = selu_(a2[2][r]);
                float og = sigmoid_(a2[3][r]);
                float c = fg*c2r[r] + ig*gg; c2r[r] = c;
                float h = og*selu_(c);
                AH2[p^1][kk2][sb2 + (q*4+r)*8] = (_Float16)h;          // raw h2
                if (t == TT-1)
                    ENCB[kk2][sb2 + (q*4+r)*8] = (_Float16)(h*s2v + t2v);
            }
        }
        p ^= 1;
    }
    __syncthreads();   // ENCB complete before w4-7 read it

    // ============ bottleneck: xz3 (w4-7) + decoder pins ============
    floatx4 xz3r[4];
    half8 wz4p[4][6], wz3p[4][2], wdnp[4];
    if (w >= 4){
        #pragma unroll
        for (int i = 0; i < 4; ++i) xz3r[i] = (floatx4){b3v[i],b3v[i],b3v[i],b3v[i]};
        #pragma unroll
        for (int kk = 0; kk < 2; ++kk){
            half8 a = *(const half8*)&ENCB[kk][l*8];
            #pragma unroll
            for (int i = 0; i < 4; ++i){
                half8 b = *(const half8*)(WS + (size_t)(FS_X3 + (4*i+w3)*2 + kk)*512 + l*8);
                xz3r[i] = MFMAH(a, b, xz3r[i]);
            }
        }
        #pragma unroll
        for (int i = 0; i < 4; ++i)
            #pragma unroll
            for (int kk = 0; kk < 2; ++kk){
                wz3p[i][kk] = *(const half8*)(WS + (size_t)(FS_Z3 + (4*i+w3)*2 + kk)*512 + l*8);
                PINA(wz3p[i][kk]);
            }
    }
    #pragma unroll
    for (int i = 0; i < 4; ++i)
        #pragma unroll
        for (int kk = 0; kk < 6; ++kk){
            wz4p[i][kk] = *(const half8*)(WS + (size_t)(FS_Z4 + (w+8*i)*6 + kk)*512 + l*8);
            PINA(wz4p[i][kk]);
        }
    if (w == 0){
        #pragma unroll
        for (int kk = 0; kk < 4; ++kk){
            wdnp[kk] = *(const half8*)(WS + (size_t)(FS_DN + kk)*512 + l*8);
            PINA(wdnp[kk]);
        }
    }

    // ============ decoder: ONE barrier/step ============
    p = 0;
    for (int tau = 0; tau < TT; ++tau){
        // --- B': z3(tau) + cell3 (waves 4-7) ---
        if (w >= 4){
            floatx4 a3[4];
            #pragma unroll
            for (int i = 0; i < 4; ++i) a3[i] = xz3r[i];
            #pragma unroll
            for (int kk = 0; kk < 2; ++kk){
                half8 a = *(const half8*)&AH3[p][kk][l*8];
                #pragma unroll
                for (int i = 0; i < 4; ++i) a3[i] = MFMAH(a, wz3p[i][kk], a3[i]);
            }
            #pragma unroll
            for (int r = 0; r < 4; ++r){
                float ig = sigmoid_(a3[0][r]);
                float fg = sigmoid_(a3[1][r]);
                float gg = selu_(a3[2][r]);
                float og = sigmoid_(a3[3][r]);
                float c = fg*c3r[r] + ig*gg; c3r[r] = c;
                float h = og*selu_(c);
                AH3[p^1][kk3][sb3 + (q*4+r)*8] = (_Float16)(h*s3v + t3v);  // hb3
            }
        }
        __syncthreads();

        // --- A': dense(tau-1) on w0, then z4(tau)+cell4 (all waves) ---
        if (w == 0 && tau >= 1){
            floatx4 ad = (floatx4){bdv,bdv,bdv,bdv};
            #pragma unroll
            for (int kk = 0; kk < 4; ++kk){
                half8 a = *(const half8*)&AH4[p][kk][l*8];
                ad = MFMAH(a, wdnp[kk], ad);
            }
            if (l15 < 8){
                #pragma unroll
                for (int r = 0; r < 4; ++r)
                    out[(size_t)(b0 + q*4 + r)*(TT*NF) + (size_t)(tau-1)*NF + l15] = ad[r];
            }
        }
        floatx4 a4[4];
        #pragma unroll
        for (int i = 0; i < 4; ++i) a4[i] = (floatx4){z4b[i],z4b[i],z4b[i],z4b[i]};
        #pragma unroll
        for (int kk = 0; kk < 6; ++kk){
            half8 a = (kk < 2) ? *(const half8*)&AH3[p^1][kk][l*8]
                               : *(const half8*)&AH4[p][kk-2][l*8];
            #pragma unroll
            for (int i = 0; i < 4; ++i) a4[i] = MFMAH(a, wz4p[i][kk], a4[i]);
        }
        #pragma unroll
        for (int r = 0; r < 4; ++r){
            float ig = sigmoid_(a4[0][r]);
            float fg = sigmoid_(a4[1][r]);
            float gg = selu_(a4[2][r]);
            float og = sigmoid_(a4[3][r]);
            float c = fg*c4r[r] + ig*gg; c4r[r] = c;
            float h = og*selu_(c);
            AH4[p^1][kk1][sb1 + (q*4+r)*8] = (_Float16)(h*s4v + t4v);      // hb4
        }
        p ^= 1;
    }
    __syncthreads();

    // epilogue: dense(TT-1) on w0
    if (w == 0){
        floatx4 ad = (floatx4){bdv,bdv,bdv,bdv};
        #pragma unroll
        for (int kk = 0; kk < 4; ++kk){
            half8 a = *(const half8*)&AH4[p][kk][l*8];
            ad = MFMAH(a, wdnp[kk], ad);
        }
        if (l15 < 8){
            #pragma unroll
            for (int r = 0; r < 4; ++r)
                out[(size_t)(b0 + q*4 + r)*(TT*NF) + (size_t)(TT-1)*NF + l15] = ad[r];
        }
    }
}

extern "C" void kernel_launch(void* const* d_in, const int* in_sizes, int n_in,
                              void* d_out, int out_size, void* d_ws, size_t ws_size,
                              hipStream_t stream) {
    const float* x   = (const float*)d_in[0];
    const float* Wk1 = (const float*)d_in[1];  const float* Wr1 = (const float*)d_in[2];
    const float* b1  = (const float*)d_in[3];
    const float* g1  = (const float*)d_in[4];  const float* be1 = (const float*)d_in[5];
    const float* m1  = (const float*)d_in[6];  const float* v1  = (const float*)d_in[7];
    const float* Wk2 = (const float*)d_in[8];  const float* Wr2 = (const float*)d_in[9];
    const float* b2  = (const float*)d_in[10];
    const float* g2  = (const float*)d_in[11]; const float* be2 = (const float*)d_in[12];
    const float* m2  = (const float*)d_in[13]; const float* v2  = (const float*)d_in[14];
    const float* Wk3 = (const float*)d_in[15]; const float* Wr3 = (const float*)d_in[16];
    const float* b3  = (const float*)d_in[17];
    const float* g3  = (const float*)d_in[18]; const float* be3 = (const float*)d_in[19];
    const float* m3  = (const float*)d_in[20]; const float* v3  = (const float*)d_in[21];
    const float* Wk4 = (const float*)d_in[22]; const float* Wr4 = (const float*)d_in[23];
    const float* b4  = (const float*)d_in[24];
    const float* g4  = (const float*)d_in[25]; const float* be4 = (const float*)d_in[26];
    const float* m4  = (const float*)d_in[27]; const float* v4  = (const float*)d_in[28];
    const float* Wd  = (const float*)d_in[29]; const float* bd  = (const float*)d_in[30];

    unsigned short* ws = (unsigned short*)d_ws;

    pack_kernel<<<dim3(N_FRAGS + 3), dim3(64), 0, stream>>>(
        Wk1, Wr1, Wk2, Wr2, Wk3, Wr3, Wk4, Wr4, Wd,
        g1, be1, m1, v1, g3, be3, m3, v3, g4, be4, m4, v4,
        b1, b3, b4, ws);
    lstm_ae_mfma<<<dim3(NBLK), dim3(NTH), 0, stream>>>(
        x, b2, bd,
        g1, be1, m1, v1, g2, be2, m2, v2,
        g3, be3, m3, v3, g4, be4, m4, v4,
        (const unsigned short*)ws, (float*)d_out);
}